// Round 1
// baseline (18059.064 us; speedup 1.0000x reference)
//
#include <hip/hip_runtime.h>
#include <hip/hip_bf16.h>

// Problem constants
#define T_LEN 2048
#define E_DIM 300
#define H_DIM 512
#define G_DIM 2048   // 4*H
#define NBLK  32     // blocks per direction in recurrent kernel
#define UPB   16     // hidden units per block (H/NBLK)

// Workspace layout (bytes). Total need ~38.8 MB.
#define WS_CTR 0           // 2 counters, 128B apart (64 u32 zeroed)
#define WS_H   4096        // hbuf: [2 dir][2 parity][2 sent][512] f32 = 16 KB
#define WS_X   32768       // x: [2 sent][2048][300] f32 = 4,915,200 B
#define WS_GX  5242880     // gx: [2d*2s][2048 t][2048 g] bf16 = 33,554,432 B

__device__ __forceinline__ float sigmoid_fast(float x) {
    return 1.f / (1.f + __expf(-x));   // graceful at +-inf, no NaN
}
__device__ __forceinline__ float tanh_fast(float x) {
    x = fminf(fmaxf(x, -15.f), 15.f);
    float e = __expf(-2.f * x);
    return (1.f - e) / (1.f + e);
}

// ---------------- k1: embedding gather + counter zeroing ----------------
__global__ void k_gather(const int* __restrict__ sentA, const int* __restrict__ sentB,
                         const float* __restrict__ emb, float* __restrict__ x,
                         unsigned int* __restrict__ ctr) {
    const int s = blockIdx.y;
    const int* sent = s ? sentB : sentA;
    const int t0 = blockIdx.x * 16;
    if (blockIdx.x == 0 && s == 0 && threadIdx.x < 64) ctr[threadIdx.x] = 0u;
    for (int idx = threadIdx.x; idx < 16 * 300; idx += 256) {
        int r = idx / 300, e = idx - r * 300;
        int t = t0 + r;
        int row = sent[t];
        x[((size_t)(s * 2048 + t)) * 300 + e] = emb[(size_t)row * 300 + e];
    }
}

// ---------------- k2: gx = x @ w_ih^T + (b_ih + b_hh), bf16 out ----------------
// grid (32 g-tiles, 64 t-tiles, 4 = d*2+s), block 256.
// Tile: 32 t-rows x 64 g-cols, K=300. x tile staged in LDS; w read from global (L1/L2).
__global__ __launch_bounds__(256) void k_gemm(const float* __restrict__ x,
                                              const float* __restrict__ w_ih,
                                              const float* __restrict__ b_ih,
                                              const float* __restrict__ b_hh,
                                              __hip_bfloat16* __restrict__ gx) {
    __shared__ float xs[32 * 304];   // stride 304 keeps float4 LDS alignment
    const int gi = blockIdx.x, ti = blockIdx.y, z = blockIdx.z;
    const int d = z >> 1, s = z & 1;
    const int t0 = ti * 32, g0 = gi * 64;

    for (int idx = threadIdx.x; idx < 32 * 75; idx += 256) {
        int r = idx / 75, c = idx - r * 75;
        float4 v = *(const float4*)(x + ((size_t)(s * 2048 + t0 + r)) * 300 + c * 4);
        *(float4*)&xs[r * 304 + c * 4] = v;
    }
    __syncthreads();

    const int tg = threadIdx.x & 15, tt = threadIdx.x >> 4;
    const float* wbase = w_ih + (size_t)d * G_DIM * E_DIM;
    float acc[2][4];
#pragma unroll
    for (int j = 0; j < 2; ++j)
#pragma unroll
        for (int i = 0; i < 4; ++i) acc[j][i] = 0.f;

    for (int e4 = 0; e4 < 75; ++e4) {
        float4 xv[2], wv[4];
#pragma unroll
        for (int j = 0; j < 2; ++j) xv[j] = *(const float4*)&xs[(tt + 16 * j) * 304 + e4 * 4];
#pragma unroll
        for (int i = 0; i < 4; ++i)
            wv[i] = *(const float4*)(wbase + (size_t)(g0 + tg + 16 * i) * 300 + e4 * 4);
#pragma unroll
        for (int j = 0; j < 2; ++j)
#pragma unroll
            for (int i = 0; i < 4; ++i)
                acc[j][i] += xv[j].x * wv[i].x + xv[j].y * wv[i].y +
                             xv[j].z * wv[i].z + xv[j].w * wv[i].w;
    }

#pragma unroll
    for (int i = 0; i < 4; ++i) {
        int g = g0 + tg + 16 * i;
        float bias = b_ih[d * G_DIM + g] + b_hh[d * G_DIM + g];
#pragma unroll
        for (int j = 0; j < 2; ++j) {
            int t = t0 + tt + 16 * j;
            int tout = d ? (T_LEN - 1 - t) : t;   // backward run: time-reversed rows
            float v = acc[j][i] + bias;
            gx[(((size_t)(d * 2 + s) * T_LEN + tout) << 11) + g] = __float2bfloat16(v);
        }
    }
}

// ---------------- k3: recurrent LSTM, 64 blocks (32 per direction) ----------------
// Block bb of direction d owns hidden units [16*bb, 16*bb+16).
// Wave w (=gate q) owns 16 gate rows; lane = k mod 64; weights 128 fp32 in registers.
// Per step: spin on agent counter -> fence -> load h (both sentences) -> FMA ->
// LDS reduce -> gates -> c/h update (wave0) -> h store + release add.
__global__ __launch_bounds__(256, 1) void k_rnn(const float* __restrict__ w_hh,
                                                const __hip_bfloat16* __restrict__ gx,
                                                float* __restrict__ hb,
                                                unsigned int* __restrict__ ctr) {
    const int tid = threadIdx.x;
    const int lane = tid & 63;
    const int w = tid >> 6;            // wave index == gate q
    const int bid = blockIdx.x;
    const int d = bid >> 5;
    const int bb = bid & 31;
    unsigned int* myctr = ctr + d * 32;   // 128 B apart

    // persistent weights: wreg[r][kb] = w_hh[d][w*512 + bb*16 + r][kb*64 + lane]
    float wreg[16][8];
#pragma unroll
    for (int r = 0; r < 16; ++r)
#pragma unroll
        for (int kb = 0; kb < 8; ++kb)
            wreg[r][kb] = w_hh[((size_t)d * G_DIM + w * 512 + bb * 16 + r) * H_DIM + kb * 64 + lane];

    __shared__ float pacc[128 * 68];   // stride 68: float4-aligned reduce reads, mild conflicts
    __shared__ float glds[128];

    // reduce-phase identity
    const int rs = tid >> 1;           // 0..127 = (row_local, sent)
    const int half = tid & 1;
    const int rl = rs >> 1;            // 0..63
    const int sR = rs & 1;
    const int qR = rl >> 4, ulR = rl & 15;
    // unit-update identity (tid < 32)
    const int sU = tid >> 4, ulU = tid & 15;
    float c_state = 0.f;

    // h0 = 0 into parity 0, then signal
    if (tid < 32) {
        __hip_atomic_store(&hb[((d * 2 + 0) * 2 + sU) * H_DIM + bb * UPB + ulU], 0.f,
                           __ATOMIC_RELAXED, __HIP_MEMORY_SCOPE_AGENT);
    }
    if (tid == 0) {
        __threadfence();
        atomicAdd(myctr, 1u);
    }

    for (int t = 0; t < T_LEN; ++t) {
        const int p = t & 1;
        const int pn = (t + 1) & 1;

        // prefetch gx[t] (independent of h) before the spin
        float gxv = 0.f;
        if (half == 0) {
            gxv = __bfloat162float(
                gx[(((size_t)(d * 2 + sR) * T_LEN + t) << 11) + qR * 512 + bb * UPB + ulR]);
        }

        // wait until all 32 blocks of this direction published h_t
        const unsigned int target = (unsigned int)(NBLK * (t + 1));
        int guard = 0;
        while (__hip_atomic_load(myctr, __ATOMIC_RELAXED, __HIP_MEMORY_SCOPE_AGENT) < target) {
            if (++guard > (1 << 22)) break;   // safety: terminate instead of hang
        }
        __threadfence();   // acquire: invalidate L1/L2 so h loads are fresh

        // load h_t for both sentences (coalesced, 16 dwords/thread)
        float hv[2][8];
        const float* hbp = hb + ((d * 2 + p) * 2) * H_DIM;
#pragma unroll
        for (int s = 0; s < 2; ++s)
#pragma unroll
            for (int kb = 0; kb < 8; ++kb)
                hv[s][kb] = hbp[s * H_DIM + kb * 64 + lane];

        // matvec partials: 16 rows x 2 sentences per lane
        float acc[16][2];
#pragma unroll
        for (int r = 0; r < 16; ++r) { acc[r][0] = 0.f; acc[r][1] = 0.f; }
#pragma unroll
        for (int kb = 0; kb < 8; ++kb) {
#pragma unroll
            for (int s = 0; s < 2; ++s) {
                float h0 = hv[s][kb];
#pragma unroll
                for (int r = 0; r < 16; ++r) acc[r][s] += wreg[r][kb] * h0;
            }
        }

        // publish partials to LDS
#pragma unroll
        for (int r = 0; r < 16; ++r)
#pragma unroll
            for (int s = 0; s < 2; ++s)
                pacc[((w * 16 + r) * 2 + s) * 68 + lane] = acc[r][s];
        __syncthreads();

        // cross-lane reduce: 2 threads per (row, sent), 32 values each
        {
            const float4* pr = (const float4*)&pacc[rs * 68 + half * 32];
            float4 sv = pr[0];
#pragma unroll
            for (int j2 = 1; j2 < 8; ++j2) {
                float4 q4 = pr[j2];
                sv.x += q4.x; sv.y += q4.y; sv.z += q4.z; sv.w += q4.w;
            }
            float v = (sv.x + sv.y) + (sv.z + sv.w);
            v += __shfl_xor(v, 1, 64);
            if (half == 0) glds[rs] = v + gxv;
        }
        __syncthreads();

        // gate nonlinearity + state update: 32 threads = 2 sents x 16 units
        if (tid < 32) {
            float xi = glds[((0 * UPB + ulU) * 2) + sU + 0];
            float xf = glds[(((UPB + ulU) * 2)) + sU];
            float xg = glds[(((2 * UPB + ulU) * 2)) + sU];
            float xo = glds[(((3 * UPB + ulU) * 2)) + sU];
            float si = sigmoid_fast(xi);
            float sf = sigmoid_fast(xf);
            float so = sigmoid_fast(xo);
            float tg = tanh_fast(xg);
            c_state = sf * c_state + si * tg;
            float h_new = so * tanh_fast(c_state);
            __hip_atomic_store(&hb[((d * 2 + pn) * 2 + sU) * H_DIM + bb * UPB + ulU], h_new,
                               __ATOMIC_RELAXED, __HIP_MEMORY_SCOPE_AGENT);
        }
        if (tid == 0) {
            __threadfence();          // release: drain h stores, write back L2
            atomicAdd(myctr, 1u);
        }
        // no end-of-step barrier needed: waves can't pass next spin until the add,
        // and the add happens after all of this step's LDS reads (post-barrier 2).
    }
}

// ---------------- k4: head ----------------
__global__ __launch_bounds__(512) void k_head(const float* __restrict__ hb,
                                              const float* __restrict__ bi_w,
                                              const float* __restrict__ bi_b,
                                              const float* __restrict__ blA,
                                              const float* __restrict__ blB,
                                              const float* __restrict__ bl_b,
                                              const float* __restrict__ out_w,
                                              const float* __restrict__ out_b,
                                              float* __restrict__ out) {
    __shared__ float enc[2][512];
    __shared__ float red[8];
    const int tid = threadIdx.x;
    const float bw0 = bi_w[0], bw1 = bi_w[1], bib = bi_b[0];
    {
        int u = tid;
        // final h lives in parity 0 (T even)
        float hfA = hb[((0 * 2 + 0) * 2 + 0) * 512 + u];
        float hbA = hb[((1 * 2 + 0) * 2 + 0) * 512 + u];
        float hfB = hb[((0 * 2 + 0) * 2 + 1) * 512 + u];
        float hbB = hb[((1 * 2 + 0) * 2 + 1) * 512 + u];
        enc[0][u] = bw0 * hfA + bw1 * hbA + bib;
        enc[1][u] = bw0 * hfB + bw1 * hbB + bib;
    }
    __syncthreads();
    const int j = tid;
    float acc = bl_b[j];
    for (int u = 0; u < 512; ++u)
        acc += enc[0][u] * blA[u * 512 + j] + enc[1][u] * blB[u * 512 + j];
    float contrib = tanh_fast(acc) * out_w[j];
#pragma unroll
    for (int m = 1; m < 64; m <<= 1) contrib += __shfl_xor(contrib, m, 64);
    if ((tid & 63) == 0) red[tid >> 6] = contrib;
    __syncthreads();
    if (tid == 0) {
        float s = 0.f;
#pragma unroll
        for (int i = 0; i < 8; ++i) s += red[i];
        s += out_b[0];
        out[0] = sigmoid_fast(s);
    }
}

extern "C" void kernel_launch(void* const* d_in, const int* in_sizes, int n_in,
                              void* d_out, int out_size, void* d_ws, size_t ws_size,
                              hipStream_t stream) {
    const int*   sentA = (const int*)d_in[0];
    const int*   sentB = (const int*)d_in[1];
    // d_in[2] = hidden (unused by forward)
    const float* emb   = (const float*)d_in[3];
    const float* w_ih  = (const float*)d_in[4];
    const float* w_hh  = (const float*)d_in[5];
    const float* b_ih  = (const float*)d_in[6];
    const float* b_hh  = (const float*)d_in[7];
    const float* bi_w  = (const float*)d_in[8];
    const float* bi_b  = (const float*)d_in[9];
    const float* blA   = (const float*)d_in[10];
    const float* blB   = (const float*)d_in[11];
    const float* bl_b  = (const float*)d_in[12];
    const float* out_w = (const float*)d_in[13];
    const float* out_b = (const float*)d_in[14];
    float* out = (float*)d_out;

    char* ws = (char*)d_ws;
    unsigned int*   ctr = (unsigned int*)(ws + WS_CTR);
    float*          hbf = (float*)(ws + WS_H);
    float*          x   = (float*)(ws + WS_X);
    __hip_bfloat16* gx  = (__hip_bfloat16*)(ws + WS_GX);

    k_gather<<<dim3(128, 2), 256, 0, stream>>>(sentA, sentB, emb, x, ctr);
    k_gemm<<<dim3(32, 64, 4), 256, 0, stream>>>(x, w_ih, b_ih, b_hh, gx);
    k_rnn<<<dim3(64), 256, 0, stream>>>(w_hh, gx, hbf, ctr);
    k_head<<<dim3(1), 512, 0, stream>>>(hbf, bi_w, bi_b, blA, blB, bl_b, out_w, out_b, out);
}

// Round 2
// 5812.299 us; speedup vs baseline: 3.1070x; 3.1070x over previous
//
#include <hip/hip_runtime.h>
#include <hip/hip_bf16.h>

// Problem constants
#define T_LEN 2048
#define E_DIM 300
#define H_DIM 512
#define G_DIM 2048   // 4*H
#define NBLK  32     // blocks per direction in recurrent kernel
#define UPB   16     // hidden units per block (H/NBLK)

// Workspace layout (bytes). Total ~38.5 MB.
// hb: (value,tag) pairs [2 dir][2 parity][2 sent][512] u64 = 16 KB
#define WS_H   0
#define WS_X   16384       // x: [2 sent][2048][300] f32 = 4,915,200 B
#define WS_GX  5242880     // gx: [d*2+s][2048 t][32 bb][4 q][16 ul] bf16 = 33,554,432 B

typedef float v2f __attribute__((ext_vector_type(2)));

__device__ __forceinline__ float sigmoid_fast(float x) {
    return 1.f / (1.f + __expf(-x));
}
__device__ __forceinline__ float tanh_fast(float x) {
    x = fminf(fmaxf(x, -15.f), 15.f);
    float e = __expf(-2.f * x);
    return (1.f - e) / (1.f + e);
}

// ---------------- k1: embedding gather ----------------
__global__ void k_gather(const int* __restrict__ sentA, const int* __restrict__ sentB,
                         const float* __restrict__ emb, float* __restrict__ x) {
    const int s = blockIdx.y;
    const int* sent = s ? sentB : sentA;
    const int t0 = blockIdx.x * 16;
    for (int idx = threadIdx.x; idx < 16 * 300; idx += 256) {
        int r = idx / 300, e = idx - r * 300;
        int t = t0 + r;
        int row = sent[t];
        x[((size_t)(s * 2048 + t)) * 300 + e] = emb[(size_t)row * 300 + e];
    }
}

// ---------------- k2: gx = x @ w_ih^T + (b_ih + b_hh), bf16, block-sliced layout ----------------
__global__ __launch_bounds__(256) void k_gemm(const float* __restrict__ x,
                                              const float* __restrict__ w_ih,
                                              const float* __restrict__ b_ih,
                                              const float* __restrict__ b_hh,
                                              __hip_bfloat16* __restrict__ gx) {
    __shared__ float xs[32 * 304];
    const int gi = blockIdx.x, ti = blockIdx.y, z = blockIdx.z;
    const int d = z >> 1, s = z & 1;
    const int t0 = ti * 32, g0 = gi * 64;

    for (int idx = threadIdx.x; idx < 32 * 75; idx += 256) {
        int r = idx / 75, c = idx - r * 75;
        float4 v = *(const float4*)(x + ((size_t)(s * 2048 + t0 + r)) * 300 + c * 4);
        *(float4*)&xs[r * 304 + c * 4] = v;
    }
    __syncthreads();

    const int tg = threadIdx.x & 15, tt = threadIdx.x >> 4;
    const float* wbase = w_ih + (size_t)d * G_DIM * E_DIM;
    float acc[2][4];
#pragma unroll
    for (int j = 0; j < 2; ++j)
#pragma unroll
        for (int i = 0; i < 4; ++i) acc[j][i] = 0.f;

    for (int e4 = 0; e4 < 75; ++e4) {
        float4 xv[2], wv[4];
#pragma unroll
        for (int j = 0; j < 2; ++j) xv[j] = *(const float4*)&xs[(tt + 16 * j) * 304 + e4 * 4];
#pragma unroll
        for (int i = 0; i < 4; ++i)
            wv[i] = *(const float4*)(wbase + (size_t)(g0 + tg + 16 * i) * 300 + e4 * 4);
#pragma unroll
        for (int j = 0; j < 2; ++j)
#pragma unroll
            for (int i = 0; i < 4; ++i)
                acc[j][i] += xv[j].x * wv[i].x + xv[j].y * wv[i].y +
                             xv[j].z * wv[i].z + xv[j].w * wv[i].w;
    }

#pragma unroll
    for (int i = 0; i < 4; ++i) {
        int g = g0 + tg + 16 * i;
        float bias = b_ih[d * G_DIM + g] + b_hh[d * G_DIM + g];
        // block-sliced position: [bb][q][ul]
        int pos = ((g >> 4) & 31) * 64 + (g >> 9) * 16 + (g & 15);
#pragma unroll
        for (int j = 0; j < 2; ++j) {
            int t = t0 + tt + 16 * j;
            int tout = d ? (T_LEN - 1 - t) : t;   // backward run: time-reversed rows
            float v = acc[j][i] + bias;
            gx[(((size_t)(d * 2 + s) * T_LEN + tout) << 11) + pos] = __float2bfloat16(v);
        }
    }
}

// ---------------- k3: recurrent LSTM, 64 blocks (32 per direction) ----------------
// h exchanged as (fp32 value, u32 step tag) 8-byte agent-scope atomic pairs.
// No fences, no counters: consumers poll the data until all tags == t.
// Double-buffer by step parity; all-to-all dependency protects slot reuse.
__global__ __launch_bounds__(256, 1) void k_rnn(const float* __restrict__ w_hh,
                                                const __hip_bfloat16* __restrict__ gx,
                                                unsigned long long* __restrict__ hb) {
    const int tid = threadIdx.x;
    const int lane = tid & 63;
    const int w = tid >> 6;            // wave index == gate q (rows w*512+bb*16 .. +16)
    const int bid = blockIdx.x;
    const int d = bid >> 5;
    const int bb = bid & 31;

    // persistent weights, row-paired for v_pk_fma_f32:
    // wreg2[r2][kb] = { W[w*512+bb*16+2*r2][kb*64+lane], W[...+2*r2+1][...] }
    v2f wreg2[8][8];
#pragma unroll
    for (int r2 = 0; r2 < 8; ++r2)
#pragma unroll
        for (int kb = 0; kb < 8; ++kb) {
            const float* wp = w_hh + ((size_t)d * G_DIM + w * 512 + bb * 16 + 2 * r2) * H_DIM
                            + kb * 64 + lane;
            v2f t2; t2.x = wp[0]; t2.y = wp[H_DIM];
            wreg2[r2][kb] = t2;
        }

    __shared__ float pacc[128 * 68];
    __shared__ float glds[128];

    const int rs = tid >> 1;           // 0..127 = row_local*2 + sent
    const int half = tid & 1;
    const int sU = tid >> 4, ulU = tid & 15;   // tid<32 identity: unit-update
    float c_state = 0.f;

    // h_0 = 0, tag 0, parity 0
    if (tid < 32) {
        __hip_atomic_store(&hb[((d * 2 + 0) * 2 + sU) * H_DIM + bb * UPB + ulU],
                           0ull, __ATOMIC_RELAXED, __HIP_MEMORY_SCOPE_AGENT);
    }

    for (int t = 0; t < T_LEN; ++t) {
        const int p = t & 1;
        const int pn = (t + 1) & 1;

        // prefetch gate inputs for this step (HBM latency overlaps the poll)
        float gxi = 0.f, gxf = 0.f, gxg = 0.f, gxo = 0.f;
        if (tid < 32) {
            const __hip_bfloat16* gp = gx + ((((size_t)(d * 2 + sU) * T_LEN + t) << 11)
                                             + bb * 64 + ulU);
            gxi = (float)gp[0];
            gxf = (float)gp[16];
            gxg = (float)gp[32];
            gxo = (float)gp[48];
        }

        // poll h_t pairs until all 16 tags match t (each wave independent)
        unsigned long long pk[2][8];
        const unsigned int tag = (unsigned int)t;
        unsigned long long* hbp = hb + ((d * 2 + p) * 2) * H_DIM;
        int guard = 0;
        bool ok;
        do {
            ok = true;
#pragma unroll
            for (int s = 0; s < 2; ++s)
#pragma unroll
                for (int kb = 0; kb < 8; ++kb)
                    pk[s][kb] = __hip_atomic_load(&hbp[s * H_DIM + kb * 64 + lane],
                                                  __ATOMIC_RELAXED, __HIP_MEMORY_SCOPE_AGENT);
#pragma unroll
            for (int s = 0; s < 2; ++s)
#pragma unroll
                for (int kb = 0; kb < 8; ++kb)
                    ok = ok && ((unsigned int)(pk[s][kb] >> 32) == tag);
        } while (!__all(ok) && ++guard < (1 << 19));

        // matvec partials: 8 row-pairs x 2 sentences per lane, packed fp32 FMA
        v2f acc2[8][2];
#pragma unroll
        for (int r2 = 0; r2 < 8; ++r2) {
            acc2[r2][0] = (v2f)(0.f);
            acc2[r2][1] = (v2f)(0.f);
        }
#pragma unroll
        for (int kb = 0; kb < 8; ++kb) {
#pragma unroll
            for (int s = 0; s < 2; ++s) {
                float h0 = __uint_as_float((unsigned int)pk[s][kb]);
                v2f h2; h2.x = h0; h2.y = h0;
#pragma unroll
                for (int r2 = 0; r2 < 8; ++r2)
                    acc2[r2][s] += wreg2[r2][kb] * h2;
            }
        }

        // publish partials
#pragma unroll
        for (int r2 = 0; r2 < 8; ++r2)
#pragma unroll
            for (int s = 0; s < 2; ++s) {
                pacc[((w * 16 + 2 * r2 + 0) * 2 + s) * 68 + lane] = acc2[r2][s].x;
                pacc[((w * 16 + 2 * r2 + 1) * 2 + s) * 68 + lane] = acc2[r2][s].y;
            }
        __syncthreads();

        // cross-lane reduce: 2 threads per (row_local, sent), 32 values each
        {
            const float4* pr = (const float4*)&pacc[rs * 68 + half * 32];
            float4 sv = pr[0];
#pragma unroll
            for (int j2 = 1; j2 < 8; ++j2) {
                float4 q4 = pr[j2];
                sv.x += q4.x; sv.y += q4.y; sv.z += q4.z; sv.w += q4.w;
            }
            float v = (sv.x + sv.y) + (sv.z + sv.w);
            v += __shfl_xor(v, 1, 64);
            if (half == 0) glds[rs] = v;
        }
        __syncthreads();

        // gates + state update + tagged h publish: 32 threads = 2 sents x 16 units
        if (tid < 32) {
            float xi = glds[((0 * UPB + ulU) * 2) + sU] + gxi;
            float xf = glds[((1 * UPB + ulU) * 2) + sU] + gxf;
            float xg = glds[((2 * UPB + ulU) * 2) + sU] + gxg;
            float xo = glds[((3 * UPB + ulU) * 2) + sU] + gxo;
            float si = sigmoid_fast(xi);
            float sf = sigmoid_fast(xf);
            float so = sigmoid_fast(xo);
            float tg = tanh_fast(xg);
            c_state = sf * c_state + si * tg;
            float h_new = so * tanh_fast(c_state);
            unsigned long long pkt = ((unsigned long long)(unsigned int)(t + 1) << 32)
                                   | (unsigned long long)__float_as_uint(h_new);
            __hip_atomic_store(&hb[((d * 2 + pn) * 2 + sU) * H_DIM + bb * UPB + ulU],
                               pkt, __ATOMIC_RELAXED, __HIP_MEMORY_SCOPE_AGENT);
        }
        // no end-of-step barrier: next poll can't pass until this block's wave0
        // published (tag t+1), and pacc/glds hazards are covered by the two
        // barriers above (see analysis in session notes).
    }
}

// ---------------- k4: head ----------------
__global__ __launch_bounds__(512) void k_head(const unsigned long long* __restrict__ hb,
                                              const float* __restrict__ bi_w,
                                              const float* __restrict__ bi_b,
                                              const float* __restrict__ blA,
                                              const float* __restrict__ blB,
                                              const float* __restrict__ bl_b,
                                              const float* __restrict__ out_w,
                                              const float* __restrict__ out_b,
                                              float* __restrict__ out) {
    __shared__ float enc[2][512];
    __shared__ float red[8];
    const int tid = threadIdx.x;
    const float bw0 = bi_w[0], bw1 = bi_w[1], bib = bi_b[0];
    {
        int u = tid;
        // final h (t=2048) lives in parity 0
        float hfA = __uint_as_float((unsigned int)hb[((0 * 2 + 0) * 2 + 0) * 512 + u]);
        float hbA = __uint_as_float((unsigned int)hb[((1 * 2 + 0) * 2 + 0) * 512 + u]);
        float hfB = __uint_as_float((unsigned int)hb[((0 * 2 + 0) * 2 + 1) * 512 + u]);
        float hbB = __uint_as_float((unsigned int)hb[((1 * 2 + 0) * 2 + 1) * 512 + u]);
        enc[0][u] = bw0 * hfA + bw1 * hbA + bib;
        enc[1][u] = bw0 * hfB + bw1 * hbB + bib;
    }
    __syncthreads();
    const int j = tid;
    float acc = bl_b[j];
    for (int u = 0; u < 512; ++u)
        acc += enc[0][u] * blA[u * 512 + j] + enc[1][u] * blB[u * 512 + j];
    float contrib = tanh_fast(acc) * out_w[j];
#pragma unroll
    for (int m = 1; m < 64; m <<= 1) contrib += __shfl_xor(contrib, m, 64);
    if ((tid & 63) == 0) red[tid >> 6] = contrib;
    __syncthreads();
    if (tid == 0) {
        float s = 0.f;
#pragma unroll
        for (int i = 0; i < 8; ++i) s += red[i];
        s += out_b[0];
        out[0] = sigmoid_fast(s);
    }
}

extern "C" void kernel_launch(void* const* d_in, const int* in_sizes, int n_in,
                              void* d_out, int out_size, void* d_ws, size_t ws_size,
                              hipStream_t stream) {
    const int*   sentA = (const int*)d_in[0];
    const int*   sentB = (const int*)d_in[1];
    // d_in[2] = hidden (unused by forward)
    const float* emb   = (const float*)d_in[3];
    const float* w_ih  = (const float*)d_in[4];
    const float* w_hh  = (const float*)d_in[5];
    const float* b_ih  = (const float*)d_in[6];
    const float* b_hh  = (const float*)d_in[7];
    const float* bi_w  = (const float*)d_in[8];
    const float* bi_b  = (const float*)d_in[9];
    const float* blA   = (const float*)d_in[10];
    const float* blB   = (const float*)d_in[11];
    const float* bl_b  = (const float*)d_in[12];
    const float* out_w = (const float*)d_in[13];
    const float* out_b = (const float*)d_in[14];
    float* out = (float*)d_out;

    char* ws = (char*)d_ws;
    unsigned long long* hbf = (unsigned long long*)(ws + WS_H);
    float*              x   = (float*)(ws + WS_X);
    __hip_bfloat16*     gx  = (__hip_bfloat16*)(ws + WS_GX);

    k_gather<<<dim3(128, 2), 256, 0, stream>>>(sentA, sentB, emb, x);
    k_gemm<<<dim3(32, 64, 4), 256, 0, stream>>>(x, w_ih, b_ih, b_hh, gx);
    k_rnn<<<dim3(64), 256, 0, stream>>>(w_hh, gx, hbf);
    k_head<<<dim3(1), 512, 0, stream>>>(hbf, bi_w, bi_b, blA, blB, bl_b, out_w, out_b, out);
}

// Round 3
// 5621.294 us; speedup vs baseline: 3.2126x; 1.0340x over previous
//
#include <hip/hip_runtime.h>
#include <hip/hip_bf16.h>

// Problem constants
#define T_LEN 2048
#define E_DIM 300
#define H_DIM 512
#define G_DIM 2048   // 4*H
#define NBLK  32     // blocks per direction in recurrent kernel
#define UPB   16     // hidden units per block (H/NBLK)

// Workspace layout (bytes). Total ~38.5 MB.
// hb: (value,tag) pairs [2 dir][2 parity][2 sent][512] u64 = 16 KB
#define WS_H   0
#define WS_X   16384       // x: [2 sent][2048][300] f32 = 4,915,200 B
#define WS_GX  5242880     // gx: [d*2+s][2048 t][32 bb][4 q][16 ul] bf16 = 33,554,432 B

typedef float v2f __attribute__((ext_vector_type(2)));

__device__ __forceinline__ float sigmoid_fast(float x) {
    return 1.f / (1.f + __expf(-x));
}
__device__ __forceinline__ float tanh_fast(float x) {
    x = fminf(fmaxf(x, -15.f), 15.f);
    float e = __expf(-2.f * x);
    return (1.f - e) / (1.f + e);
}

// ---------------- k1: embedding gather ----------------
__global__ void k_gather(const int* __restrict__ sentA, const int* __restrict__ sentB,
                         const float* __restrict__ emb, float* __restrict__ x) {
    const int s = blockIdx.y;
    const int* sent = s ? sentB : sentA;
    const int t0 = blockIdx.x * 16;
    for (int idx = threadIdx.x; idx < 16 * 300; idx += 256) {
        int r = idx / 300, e = idx - r * 300;
        int t = t0 + r;
        int row = sent[t];
        x[((size_t)(s * 2048 + t)) * 300 + e] = emb[(size_t)row * 300 + e];
    }
}

// ---------------- k2: gx = x @ w_ih^T + (b_ih + b_hh), bf16, block-sliced layout ----------------
// grid (32 gi, 64 ti, 4 = d*2+s), block 256. Both tiles staged in LDS
// (coalesced global loads); K chunked 3x100.
__global__ __launch_bounds__(256) void k_gemm(const float* __restrict__ x,
                                              const float* __restrict__ w_ih,
                                              const float* __restrict__ b_ih,
                                              const float* __restrict__ b_hh,
                                              __hip_bfloat16* __restrict__ gx) {
    // stride 108 floats (432B, 16B-aligned rows; 108 mod 32 = 12 -> <=2-way banks)
    __shared__ float xs[32 * 108];
    __shared__ float ws_[64 * 108];
    const int gi = blockIdx.x, ti = blockIdx.y, z = blockIdx.z;
    const int d = z >> 1, s = z & 1;
    const int t0 = ti * 32, g0 = gi * 64;
    const int tg = threadIdx.x & 15, tt = threadIdx.x >> 4;
    const float* wbase = w_ih + (size_t)d * G_DIM * E_DIM;

    float acc[2][4];
#pragma unroll
    for (int j = 0; j < 2; ++j)
#pragma unroll
        for (int i = 0; i < 4; ++i) acc[j][i] = 0.f;

    for (int e0 = 0; e0 < 300; e0 += 100) {
        // stage x tile: 32 rows x 25 float4
        for (int idx = threadIdx.x; idx < 32 * 25; idx += 256) {
            int r = idx / 25, c = idx - r * 25;
            float4 v = *(const float4*)(x + ((size_t)(s * 2048 + t0 + r)) * 300 + e0 + c * 4);
            *(float4*)&xs[r * 108 + c * 4] = v;
        }
        // stage w tile: 64 rows x 25 float4
        for (int idx = threadIdx.x; idx < 64 * 25; idx += 256) {
            int r = idx / 25, c = idx - r * 25;
            float4 v = *(const float4*)(wbase + (size_t)(g0 + r) * 300 + e0 + c * 4);
            *(float4*)&ws_[r * 108 + c * 4] = v;
        }
        __syncthreads();

        for (int c = 0; c < 25; ++c) {
            float4 xv[2], wv[4];
#pragma unroll
            for (int j = 0; j < 2; ++j) xv[j] = *(const float4*)&xs[(tt + 16 * j) * 108 + c * 4];
#pragma unroll
            for (int i = 0; i < 4; ++i) wv[i] = *(const float4*)&ws_[(tg + 16 * i) * 108 + c * 4];
#pragma unroll
            for (int j = 0; j < 2; ++j)
#pragma unroll
                for (int i = 0; i < 4; ++i)
                    acc[j][i] += xv[j].x * wv[i].x + xv[j].y * wv[i].y +
                                 xv[j].z * wv[i].z + xv[j].w * wv[i].w;
        }
        __syncthreads();
    }

#pragma unroll
    for (int i = 0; i < 4; ++i) {
        int g = g0 + tg + 16 * i;
        float bias = b_ih[d * G_DIM + g] + b_hh[d * G_DIM + g];
        // block-sliced position: [bb][q][ul]
        int pos = ((g >> 4) & 31) * 64 + (g >> 9) * 16 + (g & 15);
#pragma unroll
        for (int j = 0; j < 2; ++j) {
            int t = t0 + tt + 16 * j;
            int tout = d ? (T_LEN - 1 - t) : t;   // backward run: time-reversed rows
            float v = acc[j][i] + bias;
            gx[(((size_t)(d * 2 + s) * T_LEN + tout) << 11) + pos] = __float2bfloat16(v);
        }
    }
}

// ---------------- k3: recurrent LSTM, 64 blocks (32 per direction) ----------------
// h exchanged as (fp32 value, u32 step tag) u64 agent-scope atomics.
// Wave w polls ONLY its k-quarter (4 loads/lane, ping-pong pipelined),
// stages to LDS; barrier; all waves read full h from LDS.
// Gates: activations fused into reduce threads, i/f/g/o gathered by shuffle
// within 8-lane groups -> no third barrier, stores issue from all 4 waves.
__global__ __launch_bounds__(256, 1) void k_rnn(const float* __restrict__ w_hh,
                                                const __hip_bfloat16* __restrict__ gx,
                                                unsigned long long* __restrict__ hb) {
    const int tid = threadIdx.x;
    const int lane = tid & 63;
    const int w = tid >> 6;            // wave index == gate for compute phase
    // reduce/gate-phase identity: tid = (s*16+ul)*8 + q*2 + half
    const int s_g = tid >> 7;
    const int ul_g = (tid >> 3) & 15;
    const int q_g = (tid >> 1) & 3;
    const int half = tid & 1;
    const int bid = blockIdx.x;
    const int d = bid >> 5;
    const int bb = bid & 31;

    // persistent weights, row-paired: wreg2[r2][kb] = { W[w*512+bb*16+2r2][k], W[+1][k] }
    v2f wreg2[8][8];
#pragma unroll
    for (int r2 = 0; r2 < 8; ++r2)
#pragma unroll
        for (int kb = 0; kb < 8; ++kb) {
            const float* wp = w_hh + ((size_t)d * G_DIM + w * 512 + bb * 16 + 2 * r2) * H_DIM
                            + kb * 64 + lane;
            v2f t2; t2.x = wp[0]; t2.y = wp[H_DIM];
            wreg2[r2][kb] = t2;
        }

    __shared__ float hlds[2 * H_DIM];   // staged h for both sentences (4 KB)
    __shared__ float pacc[128 * 68];

    float c_state = 0.f;

    // h_0 = 0, tag 0, parity 0 (published by the 32 state-carrier threads)
    if ((tid & 7) == 0) {
        __hip_atomic_store(&hb[((d * 2 + 0) * 2 + s_g) * H_DIM + bb * UPB + ul_g],
                           0ull, __ATOMIC_RELAXED, __HIP_MEMORY_SCOPE_AGENT);
    }

    // poll indices: wave w owns k-quarter [w*128, w*128+128)
    const int i0 = 0 * H_DIM + w * 128 + lane;
    const int i1 = i0 + 64;
    const int i2 = 1 * H_DIM + w * 128 + lane;
    const int i3 = i2 + 64;

    for (int t = 0; t < T_LEN; ++t) {
        const int p = t & 1;
        const int pn = (t + 1) & 1;

        // prefetch this thread's gate input (overlaps the poll)
        float gxv = (float)gx[(((size_t)(d * 2 + s_g) * T_LEN + t) << 11)
                              + bb * 64 + q_g * 16 + ul_g];

        unsigned long long* hbp = hb + ((d * 2 + p) * 2) * H_DIM;
        const unsigned int tag = (unsigned int)t;
        unsigned long long a0, a1, a2, a3, b0, b1, b2, b3;

#define LDH(X) __hip_atomic_load(&hbp[X], __ATOMIC_RELAXED, __HIP_MEMORY_SCOPE_AGENT)
        a0 = LDH(i0); a1 = LDH(i1); a2 = LDH(i2); a3 = LDH(i3);
        int guard = 0;
        for (;;) {
            b0 = LDH(i0); b1 = LDH(i1); b2 = LDH(i2); b3 = LDH(i3);
            bool okA = ((unsigned int)(a0 >> 32) == tag) & ((unsigned int)(a1 >> 32) == tag)
                     & ((unsigned int)(a2 >> 32) == tag) & ((unsigned int)(a3 >> 32) == tag);
            if (__all(okA)) break;
            if (++guard > (1 << 20)) break;
            a0 = LDH(i0); a1 = LDH(i1); a2 = LDH(i2); a3 = LDH(i3);
            bool okB = ((unsigned int)(b0 >> 32) == tag) & ((unsigned int)(b1 >> 32) == tag)
                     & ((unsigned int)(b2 >> 32) == tag) & ((unsigned int)(b3 >> 32) == tag);
            if (__all(okB)) { a0 = b0; a1 = b1; a2 = b2; a3 = b3; break; }
            if (++guard > (1 << 20)) break;
        }
#undef LDH

        // stage this wave's quarter into LDS
        hlds[i0] = __uint_as_float((unsigned int)a0);
        hlds[i1] = __uint_as_float((unsigned int)a1);
        hlds[i2] = __uint_as_float((unsigned int)a2);
        hlds[i3] = __uint_as_float((unsigned int)a3);
        __syncthreads();   // B1: full h visible to all waves

        // load full h fragment for this lane
        float hv[2][8];
#pragma unroll
        for (int s = 0; s < 2; ++s)
#pragma unroll
            for (int kb = 0; kb < 8; ++kb)
                hv[s][kb] = hlds[s * H_DIM + kb * 64 + lane];

        // matvec partials: 8 row-pairs x 2 sentences per lane, packed fp32 FMA
        v2f acc2[8][2];
#pragma unroll
        for (int r2 = 0; r2 < 8; ++r2) {
            acc2[r2][0] = (v2f)(0.f);
            acc2[r2][1] = (v2f)(0.f);
        }
#pragma unroll
        for (int kb = 0; kb < 8; ++kb) {
#pragma unroll
            for (int s = 0; s < 2; ++s) {
                float h0 = hv[s][kb];
                v2f h2; h2.x = h0; h2.y = h0;
#pragma unroll
                for (int r2 = 0; r2 < 8; ++r2)
                    acc2[r2][s] += wreg2[r2][kb] * h2;
            }
        }

        // publish partials
#pragma unroll
        for (int r2 = 0; r2 < 8; ++r2)
#pragma unroll
            for (int s = 0; s < 2; ++s) {
                pacc[((w * 16 + 2 * r2 + 0) * 2 + s) * 68 + lane] = acc2[r2][s].x;
                pacc[((w * 16 + 2 * r2 + 1) * 2 + s) * 68 + lane] = acc2[r2][s].y;
            }
        __syncthreads();   // B2

        // reduce row (gate q_g, unit ul_g, sent s_g): 2 threads x 32 values
        const float4* pr = (const float4*)&pacc[((q_g * 16 + ul_g) * 2 + s_g) * 68 + half * 32];
        float4 sv = pr[0];
#pragma unroll
        for (int j2 = 1; j2 < 8; ++j2) {
            float4 q4 = pr[j2];
            sv.x += q4.x; sv.y += q4.y; sv.z += q4.z; sv.w += q4.w;
        }
        float v = (sv.x + sv.y) + (sv.z + sv.w);
        v += __shfl_xor(v, 1, 64);
        v += gxv;
        float act = (q_g == 2) ? tanh_fast(v) : sigmoid_fast(v);

        // gather i/f/g/o within the 8-lane group, update state, publish h
        const int g0l = lane & ~7;
        float si  = __shfl(act, g0l + 0, 64);
        float sf  = __shfl(act, g0l + 2, 64);
        float tgg = __shfl(act, g0l + 4, 64);
        float so  = __shfl(act, g0l + 6, 64);
        if ((lane & 7) == 0) {
            c_state = sf * c_state + si * tgg;
            float h_new = so * tanh_fast(c_state);
            unsigned long long pkt = ((unsigned long long)(unsigned int)(t + 1) << 32)
                                   | (unsigned long long)__float_as_uint(h_new);
            __hip_atomic_store(&hb[((d * 2 + pn) * 2 + s_g) * H_DIM + bb * UPB + ul_g],
                               pkt, __ATOMIC_RELAXED, __HIP_MEMORY_SCOPE_AGENT);
        }
        // pacc/hlds WAR across steps protected by B1/B2 (see session notes)
    }
}

// ---------------- k4: head ----------------
__global__ __launch_bounds__(512) void k_head(const unsigned long long* __restrict__ hb,
                                              const float* __restrict__ bi_w,
                                              const float* __restrict__ bi_b,
                                              const float* __restrict__ blA,
                                              const float* __restrict__ blB,
                                              const float* __restrict__ bl_b,
                                              const float* __restrict__ out_w,
                                              const float* __restrict__ out_b,
                                              float* __restrict__ out) {
    __shared__ float enc[2][512];
    __shared__ float red[8];
    const int tid = threadIdx.x;
    const float bw0 = bi_w[0], bw1 = bi_w[1], bib = bi_b[0];
    {
        int u = tid;
        // final h (t=2048) lives in parity 0
        float hfA = __uint_as_float((unsigned int)hb[((0 * 2 + 0) * 2 + 0) * 512 + u]);
        float hbA = __uint_as_float((unsigned int)hb[((1 * 2 + 0) * 2 + 0) * 512 + u]);
        float hfB = __uint_as_float((unsigned int)hb[((0 * 2 + 0) * 2 + 1) * 512 + u]);
        float hbB = __uint_as_float((unsigned int)hb[((1 * 2 + 0) * 2 + 1) * 512 + u]);
        enc[0][u] = bw0 * hfA + bw1 * hbA + bib;
        enc[1][u] = bw0 * hfB + bw1 * hbB + bib;
    }
    __syncthreads();
    const int j = tid;
    float acc = bl_b[j];
#pragma unroll 4
    for (int u = 0; u < 512; ++u)
        acc += enc[0][u] * blA[u * 512 + j] + enc[1][u] * blB[u * 512 + j];
    float contrib = tanh_fast(acc) * out_w[j];
#pragma unroll
    for (int m = 1; m < 64; m <<= 1) contrib += __shfl_xor(contrib, m, 64);
    if ((tid & 63) == 0) red[tid >> 6] = contrib;
    __syncthreads();
    if (tid == 0) {
        float s = 0.f;
#pragma unroll
        for (int i = 0; i < 8; ++i) s += red[i];
        s += out_b[0];
        out[0] = sigmoid_fast(s);
    }
}

extern "C" void kernel_launch(void* const* d_in, const int* in_sizes, int n_in,
                              void* d_out, int out_size, void* d_ws, size_t ws_size,
                              hipStream_t stream) {
    const int*   sentA = (const int*)d_in[0];
    const int*   sentB = (const int*)d_in[1];
    // d_in[2] = hidden (unused by forward)
    const float* emb   = (const float*)d_in[3];
    const float* w_ih  = (const float*)d_in[4];
    const float* w_hh  = (const float*)d_in[5];
    const float* b_ih  = (const float*)d_in[6];
    const float* b_hh  = (const float*)d_in[7];
    const float* bi_w  = (const float*)d_in[8];
    const float* bi_b  = (const float*)d_in[9];
    const float* blA   = (const float*)d_in[10];
    const float* blB   = (const float*)d_in[11];
    const float* bl_b  = (const float*)d_in[12];
    const float* out_w = (const float*)d_in[13];
    const float* out_b = (const float*)d_in[14];
    float* out = (float*)d_out;

    char* ws = (char*)d_ws;
    unsigned long long* hbf = (unsigned long long*)(ws + WS_H);
    float*              x   = (float*)(ws + WS_X);
    __hip_bfloat16*     gx  = (__hip_bfloat16*)(ws + WS_GX);

    k_gather<<<dim3(128, 2), 256, 0, stream>>>(sentA, sentB, emb, x);
    k_gemm<<<dim3(32, 64, 4), 256, 0, stream>>>(x, w_ih, b_ih, b_hh, gx);
    k_rnn<<<dim3(64), 256, 0, stream>>>(w_hh, gx, hbf);
    k_head<<<dim3(1), 512, 0, stream>>>(hbf, bi_w, bi_b, blA, blB, bl_b, out_w, out_b, out);
}